// Round 1
// baseline (1375.353 us; speedup 1.0000x reference)
//
#include <hip/hip_runtime.h>
#include <math.h>

#define NBX 168
#define NBY 480
#define NBL 6
#define PLANE (NBX * NBY)     /* 80640 bins per type plane            */
#define MAPSZ (PLANE * NBL)   /* 483840 floats = 1.9 MB               */
#define EXT 2
#define W 5
#define INV_SQRT2 0.70710678118654752440f
#define INV_CAP 0.0625f       /* 1 / SLICE_CAPACITY(16); STDXY == 1   */

// Per-axis truncated-Gaussian fragment: 5 weights + clamped bin ids.
// g[j] == 0 exactly for out-of-range bins (matches reference's where()).
__device__ __forceinline__ void axis_frag(float c, int nb, float* g, int* bc) {
    int b0 = (int)floorf(c);
    float t0 = (float)(b0 - EXT) - c;   // t for j = 0
    float e[W + 1];
#pragma unroll
    for (int k = 0; k <= W; ++k) e[k] = erff((t0 + (float)k) * INV_SQRT2);
#pragma unroll
    for (int j = 0; j < W; ++j) {
        int b = b0 - EXT + j;
        bool valid = (b >= 0) && (b < nb);
        g[j] = valid ? 0.5f * (e[j + 1] - e[j]) : 0.0f;
        int bcl = b < 0 ? 0 : b;
        bc[j] = bcl > nb - 1 ? nb - 1 : bcl;
    }
}

// Pass 1: scatter area-weighted 5x5 patches into dem[type][x][y].
__global__ void k_demand(const float* __restrict__ pos,
                         const float* __restrict__ nsx,
                         const float* __restrict__ nsy,
                         const int* __restrict__ idx,
                         const int* __restrict__ ltyp,
                         float* __restrict__ dem,
                         int n, int Linst) {
    int i = blockIdx.x * blockDim.x + threadIdx.x;
    if (i >= Linst) return;
    int id = idx[i];
    float sx = nsx[id], sy = nsy[id];
    float cx = pos[id] + 0.5f * sx;        // INV_STDX == 1
    float cy = pos[n + id] + 0.5f * sy;    // INV_STDY == 1
    float area = sx * sy;
    float gx[W], gy[W];
    int bx[W], by[W];
    axis_frag(cx, NBX, gx, bx);
    axis_frag(cy, NBY, gy, by);
    int t = ltyp[id];
    float* plane = dem + t * PLANE;
#pragma unroll
    for (int jx = 0; jx < W; ++jx) {
        float wx = gx[jx] * area;
        if (wx == 0.0f) continue;          // out-of-range bin: skip atomic
        float* row = plane + bx[jx] * NBY;
#pragma unroll
        for (int jy = 0; jy < W; ++jy) {
            float w = wx * gy[jy];
            if (w != 0.0f) atomicAdd(row + by[jy], w);
        }
    }
}

// Pass 2: compat[t][xy] = sum_l dem[l][xy] * frac[t][l]  (frac is 6x6 int)
__global__ void k_compat(const float* __restrict__ dem,
                         const int* __restrict__ frac,
                         float* __restrict__ compat) {
    int xy = blockIdx.x * blockDim.x + threadIdx.x;
    if (xy >= PLANE) return;
    float d[NBL];
#pragma unroll
    for (int l = 0; l < NBL; ++l) d[l] = dem[l * PLANE + xy];
#pragma unroll
    for (int t = 0; t < NBL; ++t) {
        float s = 0.0f;
#pragma unroll
        for (int l = 0; l < NBL; ++l) s += d[l] * (float)frac[t * NBL + l];
        compat[t * PLANE + xy] = s;
    }
}

// Pass 3: gather compat at each instance's 5x5 patch, weighted sum.
__global__ void k_gather(const float* __restrict__ pos,
                         const float* __restrict__ nsx,
                         const float* __restrict__ nsy,
                         const int* __restrict__ idx,
                         const int* __restrict__ ltyp,
                         const float* __restrict__ compat,
                         float* __restrict__ out,
                         int n, int Linst) {
    int i = blockIdx.x * blockDim.x + threadIdx.x;
    if (i >= Linst) return;
    int id = idx[i];
    float sx = nsx[id], sy = nsy[id];
    float cx = pos[id] + 0.5f * sx;
    float cy = pos[n + id] + 0.5f * sy;
    float gx[W], gy[W];
    int bx[W], by[W];
    axis_frag(cx, NBX, gx, bx);
    axis_frag(cy, NBY, gy, by);
    int t = ltyp[id];
    const float* plane = compat + t * PLANE;
    float sum = 0.0f;
#pragma unroll
    for (int jx = 0; jx < W; ++jx) {
        float wx = gx[jx];
        const float* row = plane + bx[jx] * NBY;
#pragma unroll
        for (int jy = 0; jy < W; ++jy) {
            sum += wx * gy[jy] * row[by[jy]];  // w==0 for invalid bins
        }
    }
    out[id] = sum * INV_CAP;
}

extern "C" void kernel_launch(void* const* d_in, const int* in_sizes, int n_in,
                              void* d_out, int out_size, void* d_ws, size_t ws_size,
                              hipStream_t stream) {
    const float* pos  = (const float*)d_in[0];
    const float* nsx  = (const float*)d_in[1];
    const float* nsy  = (const float*)d_in[2];
    const int*   idx  = (const int*)d_in[3];
    const int*   ltyp = (const int*)d_in[4];
    const int*   frac = (const int*)d_in[5];
    int n     = in_sizes[1];   // N instances in arrays
    int Linst = in_sizes[3];   // L active instances
    float* out = (float*)d_out;

    float* dem    = (float*)d_ws;          // MAPSZ floats
    float* compat = dem + MAPSZ;           // MAPSZ floats

    hipMemsetAsync(dem, 0, MAPSZ * sizeof(float), stream);
    hipMemsetAsync(out, 0, (size_t)out_size * sizeof(float), stream);

    const int bs = 256;
    k_demand<<<(Linst + bs - 1) / bs, bs, 0, stream>>>(pos, nsx, nsy, idx, ltyp, dem, n, Linst);
    k_compat<<<(PLANE + bs - 1) / bs, bs, 0, stream>>>(dem, frac, compat);
    k_gather<<<(Linst + bs - 1) / bs, bs, 0, stream>>>(pos, nsx, nsy, idx, ltyp, compat, out, n, Linst);
}

// Round 2
// 374.653 us; speedup vs baseline: 3.6710x; 3.6710x over previous
//
#include <hip/hip_runtime.h>
#include <math.h>

#define NBX 168
#define NBY 480
#define NBL 6
#define PLANE (NBX * NBY)
#define MAPSZ (PLANE * NBL)
#define EXT 2
#define W 5
#define INV_SQRT2 0.70710678118654752440f
#define INV_CAP 0.0625f

/* ---- spatial tiling for the scatter phase ---- */
#define TW 8                    /* tile width in x-bins  (168/8  = 21) */
#define TH 24                   /* tile height in y-bins (480/24 = 20) */
#define TX (NBX / TW)           /* 21 */
#define TY (NBY / TH)           /* 20 */
#define NT (TX * TY)            /* 420 tiles */
#define LTW (TW + 2 * EXT)      /* 12 */
#define LTH (TH + 2 * EXT)      /* 28 */
#define SLAB (NBL * LTW * LTH)  /* 2016 floats = 8064 B LDS per tile */
#define TLOC 4096               /* per-block tile-id cache in scatter */

__device__ __forceinline__ void axis_frag(float c, int nb, float* g, int* bc) {
    int b0 = (int)floorf(c);
    float t0 = (float)(b0 - EXT) - c;
    float e[W + 1];
#pragma unroll
    for (int k = 0; k <= W; ++k) e[k] = erff((t0 + (float)k) * INV_SQRT2);
#pragma unroll
    for (int j = 0; j < W; ++j) {
        int b = b0 - EXT + j;
        bool valid = (b >= 0) && (b < nb);
        g[j] = valid ? 0.5f * (e[j + 1] - e[j]) : 0.0f;
        int bcl = b < 0 ? 0 : b;
        bc[j] = bcl > nb - 1 ? nb - 1 : bcl;
    }
}

__device__ __forceinline__ int tile_of(const float* pos, const float* nsx,
                                       const float* nsy, int id, int n) {
    float cx = pos[id] + 0.5f * nsx[id];
    float cy = pos[n + id] + 0.5f * nsy[id];
    int bx = (int)floorf(cx); bx = bx < 0 ? 0 : (bx > NBX - 1 ? NBX - 1 : bx);
    int by = (int)floorf(cy); by = by < 0 ? 0 : (by > NBY - 1 ? NBY - 1 : by);
    return (bx / TW) * TY + (by / TH);
}

/* Pass A: per-tile histogram (block-aggregated in LDS). */
__global__ void k_hist(const float* __restrict__ pos, const float* __restrict__ nsx,
                       const float* __restrict__ nsy, const int* __restrict__ idx,
                       int* __restrict__ tileCount, int n, int Linst) {
    __shared__ int cnt[NT];
    for (int t = threadIdx.x; t < NT; t += blockDim.x) cnt[t] = 0;
    __syncthreads();
    int stride = gridDim.x * blockDim.x;
    for (int i = blockIdx.x * blockDim.x + threadIdx.x; i < Linst; i += stride) {
        int id = idx[i];
        atomicAdd(&cnt[tile_of(pos, nsx, nsy, id, n)], 1);
    }
    __syncthreads();
    for (int t = threadIdx.x; t < NT; t += blockDim.x)
        if (cnt[t]) atomicAdd(&tileCount[t], cnt[t]);
}

/* Pass B: exclusive scan over 420 tile counts (single block). */
__global__ void k_scan(const int* __restrict__ cnt, int* __restrict__ start,
                       int* __restrict__ cursor) {
    __shared__ int arr[512];
    int tid = threadIdx.x;
    int v = (tid < NT) ? cnt[tid] : 0;
    arr[tid] = v;
    __syncthreads();
    for (int off = 1; off < 512; off <<= 1) {
        int u = (tid >= off) ? arr[tid - off] : 0;
        __syncthreads();
        arr[tid] += u;
        __syncthreads();
    }
    if (tid < NT) { int e = arr[tid] - v; start[tid] = e; cursor[tid] = e; }
    if (tid == 0) start[NT] = arr[511];
}

/* Pass C: counting-sort scatter; block reserves per-tile ranges (one global
   atomic per tile per block), then places its instances via LDS cursors. */
__global__ void k_scatter(const float* __restrict__ pos, const float* __restrict__ nsx,
                          const float* __restrict__ nsy, const int* __restrict__ idx,
                          int* __restrict__ cursor, int* __restrict__ sorted,
                          int n, int Linst) {
    __shared__ int cnt[NT];
    __shared__ int base[NT];
    __shared__ unsigned short tloc[TLOC];
    int chunk = (Linst + gridDim.x - 1) / gridDim.x;
    int lo = blockIdx.x * chunk;
    int hi = lo + chunk; if (hi > Linst) hi = Linst;
    for (int t = threadIdx.x; t < NT; t += blockDim.x) cnt[t] = 0;
    __syncthreads();
    for (int i = lo + threadIdx.x; i < hi; i += blockDim.x) {
        int t = tile_of(pos, nsx, nsy, idx[i], n);
        int k = i - lo;
        if (k < TLOC) tloc[k] = (unsigned short)t;
        atomicAdd(&cnt[t], 1);
    }
    __syncthreads();
    for (int t = threadIdx.x; t < NT; t += blockDim.x) {
        base[t] = cnt[t] ? atomicAdd(&cursor[t], cnt[t]) : 0;
        cnt[t] = 0;                 /* reuse as local cursor */
    }
    __syncthreads();
    for (int i = lo + threadIdx.x; i < hi; i += blockDim.x) {
        int id = idx[i];
        int k = i - lo;
        int t = (k < TLOC) ? (int)tloc[k] : tile_of(pos, nsx, nsy, id, n);
        int r = atomicAdd(&cnt[t], 1);
        sorted[base[t] + r] = id;
    }
}

/* Pass D: one block per tile — accumulate 5x5 patches in LDS, store slab. */
__global__ void k_demand_tiled(const float* __restrict__ pos, const float* __restrict__ nsx,
                               const float* __restrict__ nsy, const int* __restrict__ ltyp,
                               const int* __restrict__ sorted, const int* __restrict__ start,
                               float* __restrict__ slabs, int n) {
    __shared__ float acc[SLAB];
    int t = blockIdx.x;
    int x0 = (t / TY) * TW, y0 = (t % TY) * TH;
    for (int s = threadIdx.x; s < SLAB; s += blockDim.x) acc[s] = 0.0f;
    __syncthreads();
    int lo = start[t], hi = start[t + 1];
    for (int j = lo + threadIdx.x; j < hi; j += blockDim.x) {
        int id = sorted[j];
        float sx = nsx[id], sy = nsy[id];
        float cx = pos[id] + 0.5f * sx;
        float cy = pos[n + id] + 0.5f * sy;
        float area = sx * sy;
        float gx[W], gy[W]; int bx[W], by[W];
        axis_frag(cx, NBX, gx, bx);
        axis_frag(cy, NBY, gy, by);
        int base = ltyp[id] * (LTW * LTH);
#pragma unroll
        for (int jx = 0; jx < W; ++jx) {
            float wx = gx[jx] * area;
            int row = base + (bx[jx] - x0 + EXT) * LTH - (y0 - EXT);
#pragma unroll
            for (int jy = 0; jy < W; ++jy)
                atomicAdd(&acc[row + by[jy]], wx * gy[jy]);
        }
    }
    __syncthreads();
    float* out = slabs + (size_t)t * SLAB;
    for (int s = threadIdx.x; s < SLAB; s += blockDim.x) out[s] = acc[s];
}

/* Pass E: assemble demand from overlapping slabs + 6x6 fracture einsum. */
__global__ void k_compat(const float* __restrict__ slabs, const int* __restrict__ frac,
                         float* __restrict__ compat) {
    int xy = blockIdx.x * blockDim.x + threadIdx.x;
    if (xy >= PLANE) return;
    int x = xy / NBY, y = xy % NBY;
    int tx = x / TW, xm = x % TW;
    int ty = y / TH, ym = y % TH;
    float d[NBL] = {0, 0, 0, 0, 0, 0};
    int ax0 = (xm < EXT && tx > 0) ? tx - 1 : tx;
    int ax1 = (xm >= TW - EXT && tx < TX - 1) ? tx + 1 : tx;
    int ay0 = (ym < EXT && ty > 0) ? ty - 1 : ty;
    int ay1 = (ym >= TH - EXT && ty < TY - 1) ? ty + 1 : ty;
    for (int ax = ax0; ax <= ax1; ++ax)
        for (int ay = ay0; ay <= ay1; ++ay) {
            int lx = x - (ax * TW - EXT);
            int ly = y - (ay * TH - EXT);
            const float* sl = slabs + (size_t)(ax * TY + ay) * SLAB + lx * LTH + ly;
#pragma unroll
            for (int l = 0; l < NBL; ++l) d[l] += sl[l * (LTW * LTH)];
        }
#pragma unroll
    for (int t = 0; t < NBL; ++t) {
        float s = 0.0f;
#pragma unroll
        for (int l = 0; l < NBL; ++l) s += d[l] * (float)frac[t * NBL + l];
        compat[t * PLANE + xy] = s;
    }
}

/* Pass F: per-tile gather — stage compat region in LDS, dot with weights. */
__global__ void k_gather_tiled(const float* __restrict__ pos, const float* __restrict__ nsx,
                               const float* __restrict__ nsy, const int* __restrict__ ltyp,
                               const int* __restrict__ sorted, const int* __restrict__ start,
                               const float* __restrict__ compat, float* __restrict__ out,
                               int n) {
    __shared__ float cc[SLAB];
    int t = blockIdx.x;
    int x0 = (t / TY) * TW, y0 = (t % TY) * TH;
    for (int s = threadIdx.x; s < SLAB; s += blockDim.x) {
        int l = s / (LTW * LTH), r = s % (LTW * LTH);
        int gx = x0 - EXT + r / LTH, gy = y0 - EXT + r % LTH;
        cc[s] = (gx >= 0 && gx < NBX && gy >= 0 && gy < NBY)
                    ? compat[l * PLANE + gx * NBY + gy] : 0.0f;
    }
    __syncthreads();
    int lo = start[t], hi = start[t + 1];
    for (int j = lo + threadIdx.x; j < hi; j += blockDim.x) {
        int id = sorted[j];
        float sx = nsx[id], sy = nsy[id];
        float cx = pos[id] + 0.5f * sx;
        float cy = pos[n + id] + 0.5f * sy;
        float gx[W], gy[W]; int bx[W], by[W];
        axis_frag(cx, NBX, gx, bx);
        axis_frag(cy, NBY, gy, by);
        int base = ltyp[id] * (LTW * LTH);
        float sum = 0.0f;
#pragma unroll
        for (int jx = 0; jx < W; ++jx) {
            float wx = gx[jx];
            int row = base + (bx[jx] - x0 + EXT) * LTH - (y0 - EXT);
#pragma unroll
            for (int jy = 0; jy < W; ++jy)
                sum += wx * gy[jy] * cc[row + by[jy]];
        }
        out[id] = sum * INV_CAP;
    }
}

/* ---------- fallback (round-1 path) if ws_size is too small ---------- */
__global__ void k_demand_atomic(const float* __restrict__ pos, const float* __restrict__ nsx,
                                const float* __restrict__ nsy, const int* __restrict__ idx,
                                const int* __restrict__ ltyp, float* __restrict__ dem,
                                int n, int Linst) {
    int i = blockIdx.x * blockDim.x + threadIdx.x;
    if (i >= Linst) return;
    int id = idx[i];
    float sx = nsx[id], sy = nsy[id];
    float cx = pos[id] + 0.5f * sx, cy = pos[n + id] + 0.5f * sy;
    float area = sx * sy;
    float gx[W], gy[W]; int bx[W], by[W];
    axis_frag(cx, NBX, gx, bx);
    axis_frag(cy, NBY, gy, by);
    float* plane = dem + ltyp[id] * PLANE;
#pragma unroll
    for (int jx = 0; jx < W; ++jx) {
        float wx = gx[jx] * area;
        if (wx == 0.0f) continue;
        float* row = plane + bx[jx] * NBY;
#pragma unroll
        for (int jy = 0; jy < W; ++jy) {
            float w = wx * gy[jy];
            if (w != 0.0f) atomicAdd(row + by[jy], w);
        }
    }
}
__global__ void k_compat_simple(const float* __restrict__ dem, const int* __restrict__ frac,
                                float* __restrict__ compat) {
    int xy = blockIdx.x * blockDim.x + threadIdx.x;
    if (xy >= PLANE) return;
    float d[NBL];
#pragma unroll
    for (int l = 0; l < NBL; ++l) d[l] = dem[l * PLANE + xy];
#pragma unroll
    for (int t = 0; t < NBL; ++t) {
        float s = 0.0f;
#pragma unroll
        for (int l = 0; l < NBL; ++l) s += d[l] * (float)frac[t * NBL + l];
        compat[t * PLANE + xy] = s;
    }
}
__global__ void k_gather_simple(const float* __restrict__ pos, const float* __restrict__ nsx,
                                const float* __restrict__ nsy, const int* __restrict__ idx,
                                const int* __restrict__ ltyp, const float* __restrict__ compat,
                                float* __restrict__ out, int n, int Linst) {
    int i = blockIdx.x * blockDim.x + threadIdx.x;
    if (i >= Linst) return;
    int id = idx[i];
    float sx = nsx[id], sy = nsy[id];
    float cx = pos[id] + 0.5f * sx, cy = pos[n + id] + 0.5f * sy;
    float gx[W], gy[W]; int bx[W], by[W];
    axis_frag(cx, NBX, gx, bx);
    axis_frag(cy, NBY, gy, by);
    const float* plane = compat + ltyp[id] * PLANE;
    float sum = 0.0f;
#pragma unroll
    for (int jx = 0; jx < W; ++jx) {
        float wx = gx[jx];
        const float* row = plane + bx[jx] * NBY;
#pragma unroll
        for (int jy = 0; jy < W; ++jy) sum += wx * gy[jy] * row[by[jy]];
    }
    out[id] = sum * INV_CAP;
}

extern "C" void kernel_launch(void* const* d_in, const int* in_sizes, int n_in,
                              void* d_out, int out_size, void* d_ws, size_t ws_size,
                              hipStream_t stream) {
    const float* pos  = (const float*)d_in[0];
    const float* nsx  = (const float*)d_in[1];
    const float* nsy  = (const float*)d_in[2];
    const int*   idx  = (const int*)d_in[3];
    const int*   ltyp = (const int*)d_in[4];
    const int*   frac = (const int*)d_in[5];
    int n     = in_sizes[1];
    int Linst = in_sizes[3];
    float* out = (float*)d_out;
    const int bs = 256;

    size_t need = ((size_t)NT * SLAB + MAPSZ) * 4 + (size_t)Linst * 4 + (3 * NT + 1) * 4;
    if (ws_size >= need) {
        float* slabs  = (float*)d_ws;
        float* compat = slabs + (size_t)NT * SLAB;
        int* sorted    = (int*)(compat + MAPSZ);
        int* tileCount = sorted + Linst;
        int* tileStart = tileCount + NT;      /* NT+1 entries */
        int* cursor    = tileStart + NT + 1;

        hipMemsetAsync(tileCount, 0, NT * sizeof(int), stream);
        hipMemsetAsync(out, 0, (size_t)out_size * sizeof(float), stream);

        k_hist<<<256, bs, 0, stream>>>(pos, nsx, nsy, idx, tileCount, n, Linst);
        k_scan<<<1, 512, 0, stream>>>(tileCount, tileStart, cursor);
        k_scatter<<<256, bs, 0, stream>>>(pos, nsx, nsy, idx, cursor, sorted, n, Linst);
        k_demand_tiled<<<NT, bs, 0, stream>>>(pos, nsx, nsy, ltyp, sorted, tileStart, slabs, n);
        k_compat<<<(PLANE + bs - 1) / bs, bs, 0, stream>>>(slabs, frac, compat);
        k_gather_tiled<<<NT, bs, 0, stream>>>(pos, nsx, nsy, ltyp, sorted, tileStart, compat, out, n);
    } else {
        float* dem    = (float*)d_ws;
        float* compat = dem + MAPSZ;
        hipMemsetAsync(dem, 0, MAPSZ * sizeof(float), stream);
        hipMemsetAsync(out, 0, (size_t)out_size * sizeof(float), stream);
        k_demand_atomic<<<(Linst + bs - 1) / bs, bs, 0, stream>>>(pos, nsx, nsy, idx, ltyp, dem, n, Linst);
        k_compat_simple<<<(PLANE + bs - 1) / bs, bs, 0, stream>>>(dem, frac, compat);
        k_gather_simple<<<(Linst + bs - 1) / bs, bs, 0, stream>>>(pos, nsx, nsy, idx, ltyp, compat, out, n, Linst);
    }
}

// Round 3
// 338.731 us; speedup vs baseline: 4.0603x; 1.1060x over previous
//
#include <hip/hip_runtime.h>
#include <math.h>

#define NBX 168
#define NBY 480
#define NBL 6
#define PLANE (NBX * NBY)
#define MAPSZ (PLANE * NBL)
#define EXT 2
#define W 5
#define INV_SQRT2 0.70710678118654752440f
#define INV_CAP 0.0625f

/* ---- spatial tiling ---- */
#define TW 8                    /* tile width in x-bins  (168/8  = 21) */
#define TH 12                   /* tile height in y-bins (480/12 = 40) */
#define TX (NBX / TW)           /* 21 */
#define TY (NBY / TH)           /* 40 */
#define NT (TX * TY)            /* 840 tiles */
#define LTW (TW + 2 * EXT)      /* 12 */
#define LTH (TH + 2 * EXT)      /* 16 */
#define SLAB (NBL * LTW * LTH)  /* 1152 floats = 4.6 KB LDS per tile */

#define HIST_BLOCKS 128
#define SCAT_BLOCKS 128

__device__ __forceinline__ void axis_frag(float c, int nb, float* g, int* bc) {
    int b0 = (int)floorf(c);
    float t0 = (float)(b0 - EXT) - c;
    float e[W + 1];
#pragma unroll
    for (int k = 0; k <= W; ++k) e[k] = erff((t0 + (float)k) * INV_SQRT2);
#pragma unroll
    for (int j = 0; j < W; ++j) {
        int b = b0 - EXT + j;
        bool valid = (b >= 0) && (b < nb);
        g[j] = valid ? 0.5f * (e[j + 1] - e[j]) : 0.0f;
        int bcl = b < 0 ? 0 : b;
        bc[j] = bcl > nb - 1 ? nb - 1 : bcl;
    }
}

/* Pass A: tile id per instance (ushort) + per-tile histogram. */
__global__ void k_hist(const float* __restrict__ pos, const float* __restrict__ nsx,
                       const float* __restrict__ nsy, const int* __restrict__ idx,
                       int* __restrict__ tileCount, unsigned short* __restrict__ tid16,
                       int n, int Linst) {
    __shared__ int cnt[NT];
    for (int t = threadIdx.x; t < NT; t += blockDim.x) cnt[t] = 0;
    __syncthreads();
    int stride = gridDim.x * blockDim.x;
    for (int i = blockIdx.x * blockDim.x + threadIdx.x; i < Linst; i += stride) {
        int id = idx[i];
        float cx = pos[id] + 0.5f * nsx[id];
        float cy = pos[n + id] + 0.5f * nsy[id];
        int bx = (int)floorf(cx); bx = bx < 0 ? 0 : (bx > NBX - 1 ? NBX - 1 : bx);
        int by = (int)floorf(cy); by = by < 0 ? 0 : (by > NBY - 1 ? NBY - 1 : by);
        int t = (bx / TW) * TY + (by / TH);
        tid16[i] = (unsigned short)t;
        atomicAdd(&cnt[t], 1);
    }
    __syncthreads();
    for (int t = threadIdx.x; t < NT; t += blockDim.x)
        if (cnt[t]) atomicAdd(&tileCount[t], cnt[t]);
}

/* Pass B: exclusive scan over NT tile counts (single block, 1024 thr). */
__global__ void k_scan(const int* __restrict__ cnt, int* __restrict__ start,
                       int* __restrict__ cursor) {
    __shared__ int arr[1024];
    int tid = threadIdx.x;
    int v = (tid < NT) ? cnt[tid] : 0;
    arr[tid] = v;
    __syncthreads();
    for (int off = 1; off < 1024; off <<= 1) {
        int u = (tid >= off) ? arr[tid - off] : 0;
        __syncthreads();
        arr[tid] += u;
        __syncthreads();
    }
    if (tid < NT) { int e = arr[tid] - v; start[tid] = e; cursor[tid] = e; }
    if (tid == 0) start[NT] = arr[1023];
}

/* Pass C: counting-sort that writes PAYLOADS (cx,cy,area,packed id|type),
   so downstream passes read contiguous records instead of gathering. */
__global__ void k_scatter(const float* __restrict__ pos, const float* __restrict__ nsx,
                          const float* __restrict__ nsy, const int* __restrict__ idx,
                          const int* __restrict__ ltyp,
                          const unsigned short* __restrict__ tid16,
                          int* __restrict__ cursor, float4* __restrict__ sorted,
                          int n, int Linst) {
    __shared__ int cnt[NT];
    __shared__ int base[NT];
    int chunk = (Linst + gridDim.x - 1) / gridDim.x;
    int lo = blockIdx.x * chunk;
    int hi = lo + chunk; if (hi > Linst) hi = Linst;
    for (int t = threadIdx.x; t < NT; t += blockDim.x) cnt[t] = 0;
    __syncthreads();
    for (int i = lo + threadIdx.x; i < hi; i += blockDim.x)
        atomicAdd(&cnt[tid16[i]], 1);
    __syncthreads();
    for (int t = threadIdx.x; t < NT; t += blockDim.x) {
        base[t] = cnt[t] ? atomicAdd(&cursor[t], cnt[t]) : 0;
        cnt[t] = 0;                 /* reuse as local cursor */
    }
    __syncthreads();
    for (int i = lo + threadIdx.x; i < hi; i += blockDim.x) {
        int id = idx[i];
        int t = (int)tid16[i];
        float sx = nsx[id], sy = nsy[id];
        float cx = pos[id] + 0.5f * sx;
        float cy = pos[n + id] + 0.5f * sy;
        int packed = (id << 3) | (ltyp[id] & 7);
        int r = atomicAdd(&cnt[t], 1);
        sorted[base[t] + r] = make_float4(cx, cy, sx * sy, __int_as_float(packed));
    }
}

/* Pass D: one block per tile — accumulate 5x5 patches in LDS, store slab. */
__global__ void k_demand_tiled(const float4* __restrict__ sorted,
                               const int* __restrict__ start,
                               float* __restrict__ slabs) {
    __shared__ float acc[SLAB];
    int t = blockIdx.x;
    int x0 = (t / TY) * TW, y0 = (t % TY) * TH;
    for (int s = threadIdx.x; s < SLAB; s += blockDim.x) acc[s] = 0.0f;
    __syncthreads();
    int lo = start[t], hi = start[t + 1];
    for (int j = lo + threadIdx.x; j < hi; j += blockDim.x) {
        float4 p = sorted[j];
        int typ = __float_as_int(p.w) & 7;
        float gx[W], gy[W]; int bx[W], by[W];
        axis_frag(p.x, NBX, gx, bx);
        axis_frag(p.y, NBY, gy, by);
        int bse = typ * (LTW * LTH);
#pragma unroll
        for (int jx = 0; jx < W; ++jx) {
            float wx = gx[jx] * p.z;
            int row = bse + (bx[jx] - x0 + EXT) * LTH - (y0 - EXT);
#pragma unroll
            for (int jy = 0; jy < W; ++jy)
                atomicAdd(&acc[row + by[jy]], wx * gy[jy]);
        }
    }
    __syncthreads();
    float* o = slabs + (size_t)t * SLAB;
    for (int s = threadIdx.x; s < SLAB; s += blockDim.x) o[s] = acc[s];
}

/* Pass E: assemble demand from overlapping slabs + 6x6 fracture einsum. */
__global__ void k_compat(const float* __restrict__ slabs, const int* __restrict__ frac,
                         float* __restrict__ compat) {
    int xy = blockIdx.x * blockDim.x + threadIdx.x;
    if (xy >= PLANE) return;
    int x = xy / NBY, y = xy % NBY;
    int tx = x / TW, xm = x % TW;
    int ty = y / TH, ym = y % TH;
    float d[NBL] = {0, 0, 0, 0, 0, 0};
    int ax0 = (xm < EXT && tx > 0) ? tx - 1 : tx;
    int ax1 = (xm >= TW - EXT && tx < TX - 1) ? tx + 1 : tx;
    int ay0 = (ym < EXT && ty > 0) ? ty - 1 : ty;
    int ay1 = (ym >= TH - EXT && ty < TY - 1) ? ty + 1 : ty;
    for (int ax = ax0; ax <= ax1; ++ax)
        for (int ay = ay0; ay <= ay1; ++ay) {
            int lx = x - (ax * TW - EXT);
            int ly = y - (ay * TH - EXT);
            const float* sl = slabs + (size_t)(ax * TY + ay) * SLAB + lx * LTH + ly;
#pragma unroll
            for (int l = 0; l < NBL; ++l) d[l] += sl[l * (LTW * LTH)];
        }
#pragma unroll
    for (int t = 0; t < NBL; ++t) {
        float s = 0.0f;
#pragma unroll
        for (int l = 0; l < NBL; ++l) s += d[l] * (float)frac[t * NBL + l];
        compat[t * PLANE + xy] = s;
    }
}

/* Pass F: per-tile gather — stage compat region in LDS, dot with weights. */
__global__ void k_gather_tiled(const float4* __restrict__ sorted,
                               const int* __restrict__ start,
                               const float* __restrict__ compat,
                               float* __restrict__ out) {
    __shared__ float cc[SLAB];
    int t = blockIdx.x;
    int x0 = (t / TY) * TW, y0 = (t % TY) * TH;
    for (int s = threadIdx.x; s < SLAB; s += blockDim.x) {
        int l = s / (LTW * LTH), r = s % (LTW * LTH);
        int gx = x0 - EXT + r / LTH, gy = y0 - EXT + r % LTH;
        cc[s] = (gx >= 0 && gx < NBX && gy >= 0 && gy < NBY)
                    ? compat[l * PLANE + gx * NBY + gy] : 0.0f;
    }
    __syncthreads();
    int lo = start[t], hi = start[t + 1];
    for (int j = lo + threadIdx.x; j < hi; j += blockDim.x) {
        float4 p = sorted[j];
        int packed = __float_as_int(p.w);
        int typ = packed & 7, id = packed >> 3;
        float gx[W], gy[W]; int bx[W], by[W];
        axis_frag(p.x, NBX, gx, bx);
        axis_frag(p.y, NBY, gy, by);
        int bse = typ * (LTW * LTH);
        float sum = 0.0f;
#pragma unroll
        for (int jx = 0; jx < W; ++jx) {
            float wx = gx[jx];
            int row = bse + (bx[jx] - x0 + EXT) * LTH - (y0 - EXT);
#pragma unroll
            for (int jy = 0; jy < W; ++jy)
                sum += wx * gy[jy] * cc[row + by[jy]];
        }
        out[id] = sum * INV_CAP;
    }
}

/* ---------- fallback (round-1 path) if ws_size is too small ---------- */
__global__ void k_demand_atomic(const float* __restrict__ pos, const float* __restrict__ nsx,
                                const float* __restrict__ nsy, const int* __restrict__ idx,
                                const int* __restrict__ ltyp, float* __restrict__ dem,
                                int n, int Linst) {
    int i = blockIdx.x * blockDim.x + threadIdx.x;
    if (i >= Linst) return;
    int id = idx[i];
    float sx = nsx[id], sy = nsy[id];
    float cx = pos[id] + 0.5f * sx, cy = pos[n + id] + 0.5f * sy;
    float area = sx * sy;
    float gx[W], gy[W]; int bx[W], by[W];
    axis_frag(cx, NBX, gx, bx);
    axis_frag(cy, NBY, gy, by);
    float* plane = dem + ltyp[id] * PLANE;
#pragma unroll
    for (int jx = 0; jx < W; ++jx) {
        float wx = gx[jx] * area;
        if (wx == 0.0f) continue;
        float* row = plane + bx[jx] * NBY;
#pragma unroll
        for (int jy = 0; jy < W; ++jy) {
            float w = wx * gy[jy];
            if (w != 0.0f) atomicAdd(row + by[jy], w);
        }
    }
}
__global__ void k_compat_simple(const float* __restrict__ dem, const int* __restrict__ frac,
                                float* __restrict__ compat) {
    int xy = blockIdx.x * blockDim.x + threadIdx.x;
    if (xy >= PLANE) return;
    float d[NBL];
#pragma unroll
    for (int l = 0; l < NBL; ++l) d[l] = dem[l * PLANE + xy];
#pragma unroll
    for (int t = 0; t < NBL; ++t) {
        float s = 0.0f;
#pragma unroll
        for (int l = 0; l < NBL; ++l) s += d[l] * (float)frac[t * NBL + l];
        compat[t * PLANE + xy] = s;
    }
}
__global__ void k_gather_simple(const float* __restrict__ pos, const float* __restrict__ nsx,
                                const float* __restrict__ nsy, const int* __restrict__ idx,
                                const int* __restrict__ ltyp, const float* __restrict__ compat,
                                float* __restrict__ out, int n, int Linst) {
    int i = blockIdx.x * blockDim.x + threadIdx.x;
    if (i >= Linst) return;
    int id = idx[i];
    float sx = nsx[id], sy = nsy[id];
    float cx = pos[id] + 0.5f * sx, cy = pos[n + id] + 0.5f * sy;
    float gx[W], gy[W]; int bx[W], by[W];
    axis_frag(cx, NBX, gx, bx);
    axis_frag(cy, NBY, gy, by);
    const float* plane = compat + ltyp[id] * PLANE;
    float sum = 0.0f;
#pragma unroll
    for (int jx = 0; jx < W; ++jx) {
        float wx = gx[jx];
        const float* row = plane + bx[jx] * NBY;
#pragma unroll
        for (int jy = 0; jy < W; ++jy) sum += wx * gy[jy] * row[by[jy]];
    }
    out[id] = sum * INV_CAP;
}

extern "C" void kernel_launch(void* const* d_in, const int* in_sizes, int n_in,
                              void* d_out, int out_size, void* d_ws, size_t ws_size,
                              hipStream_t stream) {
    const float* pos  = (const float*)d_in[0];
    const float* nsx  = (const float*)d_in[1];
    const float* nsy  = (const float*)d_in[2];
    const int*   idx  = (const int*)d_in[3];
    const int*   ltyp = (const int*)d_in[4];
    const int*   frac = (const int*)d_in[5];
    int n     = in_sizes[1];
    int Linst = in_sizes[3];
    float* out = (float*)d_out;
    const int bs = 256;

    size_t need = (size_t)Linst * 16                      /* sorted payloads */
                + (size_t)NT * SLAB * 4                   /* slabs           */
                + (size_t)MAPSZ * 4                       /* compat          */
                + (size_t)(3 * NT + 1) * 4                /* counters        */
                + (size_t)Linst * 2;                      /* tid16           */
    if (ws_size >= need) {
        float4* sorted  = (float4*)d_ws;
        float* slabs    = (float*)(sorted + Linst);
        float* compat   = slabs + (size_t)NT * SLAB;
        int* tileCount  = (int*)(compat + MAPSZ);
        int* tileStart  = tileCount + NT;                 /* NT+1 entries */
        int* cursor     = tileStart + NT + 1;
        unsigned short* tid16 = (unsigned short*)(cursor + NT);

        hipMemsetAsync(tileCount, 0, NT * sizeof(int), stream);
        hipMemsetAsync(out, 0, (size_t)out_size * sizeof(float), stream);

        k_hist<<<HIST_BLOCKS, bs, 0, stream>>>(pos, nsx, nsy, idx, tileCount, tid16, n, Linst);
        k_scan<<<1, 1024, 0, stream>>>(tileCount, tileStart, cursor);
        k_scatter<<<SCAT_BLOCKS, bs, 0, stream>>>(pos, nsx, nsy, idx, ltyp, tid16, cursor,
                                                  sorted, n, Linst);
        k_demand_tiled<<<NT, bs, 0, stream>>>(sorted, tileStart, slabs);
        k_compat<<<(PLANE + bs - 1) / bs, bs, 0, stream>>>(slabs, frac, compat);
        k_gather_tiled<<<NT, bs, 0, stream>>>(sorted, tileStart, compat, out);
    } else {
        float* dem    = (float*)d_ws;
        float* compat = dem + MAPSZ;
        hipMemsetAsync(dem, 0, MAPSZ * sizeof(float), stream);
        hipMemsetAsync(out, 0, (size_t)out_size * sizeof(float), stream);
        k_demand_atomic<<<(Linst + bs - 1) / bs, bs, 0, stream>>>(pos, nsx, nsy, idx, ltyp, dem, n, Linst);
        k_compat_simple<<<(PLANE + bs - 1) / bs, bs, 0, stream>>>(dem, frac, compat);
        k_gather_simple<<<(Linst + bs - 1) / bs, bs, 0, stream>>>(pos, nsx, nsy, idx, ltyp, compat, out, n, Linst);
    }
}

// Round 4
// 334.391 us; speedup vs baseline: 4.1130x; 1.0130x over previous
//
#include <hip/hip_runtime.h>
#include <math.h>

#define NBX 168
#define NBY 480
#define NBL 6
#define PLANE (NBX * NBY)
#define MAPSZ (PLANE * NBL)
#define EXT 2
#define W 5
#define INV_SQRT2 0.70710678118654752440f
#define INV_CAP 0.0625f

/* ---- spatial tiling ---- */
#define TW 8                    /* tile width in x-bins  (168/8  = 21) */
#define TH 12                   /* tile height in y-bins (480/12 = 40) */
#define TX (NBX / TW)           /* 21 */
#define TY (NBY / TH)           /* 40 */
#define NT (TX * TY)            /* 840 tiles */
#define LTW (TW + 2 * EXT)      /* 12 */
#define LTH (TH + 2 * EXT)      /* 16 */
#define SLAB (NBL * LTW * LTH)  /* 1152 floats = 4.6 KB LDS per tile */

#define HIST_BLOCKS 128
#define SCAT_BLOCKS 128

/* Branch-free erf, Abramowitz-Stegun 7.1.26 (|err| <= 1.5e-7).
   Our arguments are bounded: t in (-3,3], so |x| <= 3/sqrt(2) ~ 2.14.
   Replaces OCML erff, whose branchy call serialized the whole kernel. */
__device__ __forceinline__ float erf_fast(float x) {
    float ax = fabsf(x);
    float t = __builtin_amdgcn_rcpf(fmaf(0.3275911f, ax, 1.0f));
    float p = fmaf(1.061405429f, t, -1.453152027f);
    p = fmaf(p, t, 1.421413741f);
    p = fmaf(p, t, -0.284496736f);
    p = fmaf(p, t, 0.254829592f);
    p = p * t;
    float e = __expf(-ax * ax);
    float r = fmaf(-p, e, 1.0f);
    return copysignf(r, x);
}

__device__ __forceinline__ void axis_frag(float c, int nb, float* g, int* bc) {
    int b0 = (int)floorf(c);
    float t0 = (float)(b0 - EXT) - c;
    float e[W + 1];
#pragma unroll
    for (int k = 0; k <= W; ++k) e[k] = erf_fast((t0 + (float)k) * INV_SQRT2);
#pragma unroll
    for (int j = 0; j < W; ++j) {
        int b = b0 - EXT + j;
        bool valid = (b >= 0) && (b < nb);
        g[j] = valid ? 0.5f * (e[j + 1] - e[j]) : 0.0f;
        int bcl = b < 0 ? 0 : b;
        bc[j] = bcl > nb - 1 ? nb - 1 : bcl;
    }
}

/* Pass A: tile id per instance (ushort) + per-tile histogram. */
__global__ void k_hist(const float* __restrict__ pos, const float* __restrict__ nsx,
                       const float* __restrict__ nsy, const int* __restrict__ idx,
                       int* __restrict__ tileCount, unsigned short* __restrict__ tid16,
                       int n, int Linst) {
    __shared__ int cnt[NT];
    for (int t = threadIdx.x; t < NT; t += blockDim.x) cnt[t] = 0;
    __syncthreads();
    int stride = gridDim.x * blockDim.x;
    for (int i = blockIdx.x * blockDim.x + threadIdx.x; i < Linst; i += stride) {
        int id = idx[i];
        float cx = pos[id] + 0.5f * nsx[id];
        float cy = pos[n + id] + 0.5f * nsy[id];
        int bx = (int)floorf(cx); bx = bx < 0 ? 0 : (bx > NBX - 1 ? NBX - 1 : bx);
        int by = (int)floorf(cy); by = by < 0 ? 0 : (by > NBY - 1 ? NBY - 1 : by);
        int t = (bx / TW) * TY + (by / TH);
        tid16[i] = (unsigned short)t;
        atomicAdd(&cnt[t], 1);
    }
    __syncthreads();
    for (int t = threadIdx.x; t < NT; t += blockDim.x)
        if (cnt[t]) atomicAdd(&tileCount[t], cnt[t]);
}

/* Pass B: exclusive scan over NT tile counts (single block, 1024 thr). */
__global__ void k_scan(const int* __restrict__ cnt, int* __restrict__ start,
                       int* __restrict__ cursor) {
    __shared__ int arr[1024];
    int tid = threadIdx.x;
    int v = (tid < NT) ? cnt[tid] : 0;
    arr[tid] = v;
    __syncthreads();
    for (int off = 1; off < 1024; off <<= 1) {
        int u = (tid >= off) ? arr[tid - off] : 0;
        __syncthreads();
        arr[tid] += u;
        __syncthreads();
    }
    if (tid < NT) { int e = arr[tid] - v; start[tid] = e; cursor[tid] = e; }
    if (tid == 0) start[NT] = arr[1023];
}

/* Pass C: counting-sort that writes PAYLOADS (cx,cy,area,packed id|type). */
__global__ void k_scatter(const float* __restrict__ pos, const float* __restrict__ nsx,
                          const float* __restrict__ nsy, const int* __restrict__ idx,
                          const int* __restrict__ ltyp,
                          const unsigned short* __restrict__ tid16,
                          int* __restrict__ cursor, float4* __restrict__ sorted,
                          int n, int Linst) {
    __shared__ int cnt[NT];
    __shared__ int base[NT];
    int chunk = (Linst + gridDim.x - 1) / gridDim.x;
    int lo = blockIdx.x * chunk;
    int hi = lo + chunk; if (hi > Linst) hi = Linst;
    for (int t = threadIdx.x; t < NT; t += blockDim.x) cnt[t] = 0;
    __syncthreads();
    for (int i = lo + threadIdx.x; i < hi; i += blockDim.x)
        atomicAdd(&cnt[tid16[i]], 1);
    __syncthreads();
    for (int t = threadIdx.x; t < NT; t += blockDim.x) {
        base[t] = cnt[t] ? atomicAdd(&cursor[t], cnt[t]) : 0;
        cnt[t] = 0;                 /* reuse as local cursor */
    }
    __syncthreads();
    for (int i = lo + threadIdx.x; i < hi; i += blockDim.x) {
        int id = idx[i];
        int t = (int)tid16[i];
        float sx = nsx[id], sy = nsy[id];
        float cx = pos[id] + 0.5f * sx;
        float cy = pos[n + id] + 0.5f * sy;
        int packed = (id << 3) | (ltyp[id] & 7);
        int r = atomicAdd(&cnt[t], 1);
        sorted[base[t] + r] = make_float4(cx, cy, sx * sy, __int_as_float(packed));
    }
}

/* Pass D: one block per tile — accumulate 5x5 patches in LDS, store slab. */
__global__ void k_demand_tiled(const float4* __restrict__ sorted,
                               const int* __restrict__ start,
                               float* __restrict__ slabs) {
    __shared__ float acc[SLAB];
    int t = blockIdx.x;
    int x0 = (t / TY) * TW, y0 = (t % TY) * TH;
    for (int s = threadIdx.x; s < SLAB; s += blockDim.x) acc[s] = 0.0f;
    __syncthreads();
    int lo = start[t], hi = start[t + 1];
    for (int j = lo + threadIdx.x; j < hi; j += blockDim.x) {
        float4 p = sorted[j];
        int typ = __float_as_int(p.w) & 7;
        float gx[W], gy[W]; int bx[W], by[W];
        axis_frag(p.x, NBX, gx, bx);
        axis_frag(p.y, NBY, gy, by);
        int bse = typ * (LTW * LTH);
#pragma unroll
        for (int jx = 0; jx < W; ++jx) {
            float wx = gx[jx] * p.z;
            int row = bse + (bx[jx] - x0 + EXT) * LTH - (y0 - EXT);
#pragma unroll
            for (int jy = 0; jy < W; ++jy)
                atomicAdd(&acc[row + by[jy]], wx * gy[jy]);
        }
    }
    __syncthreads();
    float* o = slabs + (size_t)t * SLAB;
    for (int s = threadIdx.x; s < SLAB; s += blockDim.x) o[s] = acc[s];
}

/* Pass E: assemble demand from overlapping slabs + 6x6 fracture einsum. */
__global__ void k_compat(const float* __restrict__ slabs, const int* __restrict__ frac,
                         float* __restrict__ compat) {
    int xy = blockIdx.x * blockDim.x + threadIdx.x;
    if (xy >= PLANE) return;
    int x = xy / NBY, y = xy % NBY;
    int tx = x / TW, xm = x % TW;
    int ty = y / TH, ym = y % TH;
    float d[NBL] = {0, 0, 0, 0, 0, 0};
    int ax0 = (xm < EXT && tx > 0) ? tx - 1 : tx;
    int ax1 = (xm >= TW - EXT && tx < TX - 1) ? tx + 1 : tx;
    int ay0 = (ym < EXT && ty > 0) ? ty - 1 : ty;
    int ay1 = (ym >= TH - EXT && ty < TY - 1) ? ty + 1 : ty;
    for (int ax = ax0; ax <= ax1; ++ax)
        for (int ay = ay0; ay <= ay1; ++ay) {
            int lx = x - (ax * TW - EXT);
            int ly = y - (ay * TH - EXT);
            const float* sl = slabs + (size_t)(ax * TY + ay) * SLAB + lx * LTH + ly;
#pragma unroll
            for (int l = 0; l < NBL; ++l) d[l] += sl[l * (LTW * LTH)];
        }
#pragma unroll
    for (int t = 0; t < NBL; ++t) {
        float s = 0.0f;
#pragma unroll
        for (int l = 0; l < NBL; ++l) s += d[l] * (float)frac[t * NBL + l];
        compat[t * PLANE + xy] = s;
    }
}

/* Pass F: per-tile gather — stage compat region in LDS, dot with weights. */
__global__ void k_gather_tiled(const float4* __restrict__ sorted,
                               const int* __restrict__ start,
                               const float* __restrict__ compat,
                               float* __restrict__ out) {
    __shared__ float cc[SLAB];
    int t = blockIdx.x;
    int x0 = (t / TY) * TW, y0 = (t % TY) * TH;
    for (int s = threadIdx.x; s < SLAB; s += blockDim.x) {
        int l = s / (LTW * LTH), r = s % (LTW * LTH);
        int gx = x0 - EXT + r / LTH, gy = y0 - EXT + r % LTH;
        cc[s] = (gx >= 0 && gx < NBX && gy >= 0 && gy < NBY)
                    ? compat[l * PLANE + gx * NBY + gy] : 0.0f;
    }
    __syncthreads();
    int lo = start[t], hi = start[t + 1];
    for (int j = lo + threadIdx.x; j < hi; j += blockDim.x) {
        float4 p = sorted[j];
        int packed = __float_as_int(p.w);
        int typ = packed & 7, id = packed >> 3;
        float gx[W], gy[W]; int bx[W], by[W];
        axis_frag(p.x, NBX, gx, bx);
        axis_frag(p.y, NBY, gy, by);
        int bse = typ * (LTW * LTH);
        float sum = 0.0f;
#pragma unroll
        for (int jx = 0; jx < W; ++jx) {
            float wx = gx[jx];
            int row = bse + (bx[jx] - x0 + EXT) * LTH - (y0 - EXT);
#pragma unroll
            for (int jy = 0; jy < W; ++jy)
                sum += wx * gy[jy] * cc[row + by[jy]];
        }
        out[id] = sum * INV_CAP;
    }
}

/* ---------- fallback (round-1 path) if ws_size is too small ---------- */
__global__ void k_demand_atomic(const float* __restrict__ pos, const float* __restrict__ nsx,
                                const float* __restrict__ nsy, const int* __restrict__ idx,
                                const int* __restrict__ ltyp, float* __restrict__ dem,
                                int n, int Linst) {
    int i = blockIdx.x * blockDim.x + threadIdx.x;
    if (i >= Linst) return;
    int id = idx[i];
    float sx = nsx[id], sy = nsy[id];
    float cx = pos[id] + 0.5f * sx, cy = pos[n + id] + 0.5f * sy;
    float area = sx * sy;
    float gx[W], gy[W]; int bx[W], by[W];
    axis_frag(cx, NBX, gx, bx);
    axis_frag(cy, NBY, gy, by);
    float* plane = dem + ltyp[id] * PLANE;
#pragma unroll
    for (int jx = 0; jx < W; ++jx) {
        float wx = gx[jx] * area;
        if (wx == 0.0f) continue;
        float* row = plane + bx[jx] * NBY;
#pragma unroll
        for (int jy = 0; jy < W; ++jy) {
            float w = wx * gy[jy];
            if (w != 0.0f) atomicAdd(row + by[jy], w);
        }
    }
}
__global__ void k_compat_simple(const float* __restrict__ dem, const int* __restrict__ frac,
                                float* __restrict__ compat) {
    int xy = blockIdx.x * blockDim.x + threadIdx.x;
    if (xy >= PLANE) return;
    float d[NBL];
#pragma unroll
    for (int l = 0; l < NBL; ++l) d[l] = dem[l * PLANE + xy];
#pragma unroll
    for (int t = 0; t < NBL; ++t) {
        float s = 0.0f;
#pragma unroll
        for (int l = 0; l < NBL; ++l) s += d[l] * (float)frac[t * NBL + l];
        compat[t * PLANE + xy] = s;
    }
}
__global__ void k_gather_simple(const float* __restrict__ pos, const float* __restrict__ nsx,
                                const float* __restrict__ nsy, const int* __restrict__ idx,
                                const int* __restrict__ ltyp, const float* __restrict__ compat,
                                float* __restrict__ out, int n, int Linst) {
    int i = blockIdx.x * blockDim.x + threadIdx.x;
    if (i >= Linst) return;
    int id = idx[i];
    float sx = nsx[id], sy = nsy[id];
    float cx = pos[id] + 0.5f * sx, cy = pos[n + id] + 0.5f * sy;
    float gx[W], gy[W]; int bx[W], by[W];
    axis_frag(cx, NBX, gx, bx);
    axis_frag(cy, NBY, gy, by);
    const float* plane = compat + ltyp[id] * PLANE;
    float sum = 0.0f;
#pragma unroll
    for (int jx = 0; jx < W; ++jx) {
        float wx = gx[jx];
        const float* row = plane + bx[jx] * NBY;
#pragma unroll
        for (int jy = 0; jy < W; ++jy) sum += wx * gy[jy] * row[by[jy]];
    }
    out[id] = sum * INV_CAP;
}

extern "C" void kernel_launch(void* const* d_in, const int* in_sizes, int n_in,
                              void* d_out, int out_size, void* d_ws, size_t ws_size,
                              hipStream_t stream) {
    const float* pos  = (const float*)d_in[0];
    const float* nsx  = (const float*)d_in[1];
    const float* nsy  = (const float*)d_in[2];
    const int*   idx  = (const int*)d_in[3];
    const int*   ltyp = (const int*)d_in[4];
    const int*   frac = (const int*)d_in[5];
    int n     = in_sizes[1];
    int Linst = in_sizes[3];
    float* out = (float*)d_out;
    const int bs = 256;

    size_t need = (size_t)Linst * 16                      /* sorted payloads */
                + (size_t)NT * SLAB * 4                   /* slabs           */
                + (size_t)MAPSZ * 4                       /* compat          */
                + (size_t)(3 * NT + 1) * 4                /* counters        */
                + (size_t)Linst * 2;                      /* tid16           */
    if (ws_size >= need) {
        float4* sorted  = (float4*)d_ws;
        float* slabs    = (float*)(sorted + Linst);
        float* compat   = slabs + (size_t)NT * SLAB;
        int* tileCount  = (int*)(compat + MAPSZ);
        int* tileStart  = tileCount + NT;                 /* NT+1 entries */
        int* cursor     = tileStart + NT + 1;
        unsigned short* tid16 = (unsigned short*)(cursor + NT);

        hipMemsetAsync(tileCount, 0, NT * sizeof(int), stream);
        hipMemsetAsync(out, 0, (size_t)out_size * sizeof(float), stream);

        k_hist<<<HIST_BLOCKS, bs, 0, stream>>>(pos, nsx, nsy, idx, tileCount, tid16, n, Linst);
        k_scan<<<1, 1024, 0, stream>>>(tileCount, tileStart, cursor);
        k_scatter<<<SCAT_BLOCKS, bs, 0, stream>>>(pos, nsx, nsy, idx, ltyp, tid16, cursor,
                                                  sorted, n, Linst);
        k_demand_tiled<<<NT, bs, 0, stream>>>(sorted, tileStart, slabs);
        k_compat<<<(PLANE + bs - 1) / bs, bs, 0, stream>>>(slabs, frac, compat);
        k_gather_tiled<<<NT, bs, 0, stream>>>(sorted, tileStart, compat, out);
    } else {
        float* dem    = (float*)d_ws;
        float* compat = dem + MAPSZ;
        hipMemsetAsync(dem, 0, MAPSZ * sizeof(float), stream);
        hipMemsetAsync(out, 0, (size_t)out_size * sizeof(float), stream);
        k_demand_atomic<<<(Linst + bs - 1) / bs, bs, 0, stream>>>(pos, nsx, nsy, idx, ltyp, dem, n, Linst);
        k_compat_simple<<<(PLANE + bs - 1) / bs, bs, 0, stream>>>(dem, frac, compat);
        k_gather_simple<<<(Linst + bs - 1) / bs, bs, 0, stream>>>(pos, nsx, nsy, idx, ltyp, compat, out, n, Linst);
    }
}